// Round 1
// baseline (1641.961 us; speedup 1.0000x reference)
//
#include <hip/hip_runtime.h>

// Problem constants (reference: B=65536, Q=128, S=8, U=32)
#define Q   128
#define S   8
#define U   32
#define QC  32     // q per block
#define RPB 16     // rows per block
#define NR  2      // rows per thread

// LDS strides (floats). W1 row stride 260: 16B-aligned (1040B), 260%32==4 ->
// lanes q..q+7 start at banks 0,4,..28 -> optimal 4-phase ds_read_b128.
#define W1_STRIDE 260
#define BW_STRIDE 36

__global__ __launch_bounds__(256, 3) void divenc_kernel(
    const float* __restrict__ x, const float* __restrict__ W1,
    const float* __restrict__ b1, const float* __restrict__ W2,
    const float* __restrict__ b2, float* __restrict__ out, int B)
{
    __shared__ __align__(16) float w1s[QC * W1_STRIDE];
    __shared__ __align__(16) float b1s[QC * BW_STRIDE];
    __shared__ __align__(16) float w2s[QC * BW_STRIDE];
    __shared__ float b2s[QC];

    const int t   = threadIdx.x;
    const int bid = blockIdx.x;
    const int qc  = bid & 3;          // Q/QC = 4 chunks
    const int qb  = qc * QC;
    const long rbase = (long)(bid >> 2) * RPB;

    // ---- stage W1 chunk: 32 q * 256 floats = 2048 float4, 8 per thread ----
    {
        const float4* W1v = (const float4*)(W1 + (long)qb * S * U);
        #pragma unroll
        for (int k = 0; k < 8; ++k) {
            int i = t + k * 256;          // float4 index 0..2047
            float4 v = W1v[i];
            int ql = i >> 6;              // 4i/256
            int g  = i & 63;              // (4i%256)/4
            *(float4*)&w1s[ql * W1_STRIDE + g * 4] = v;
        }
    }
    // ---- stage b1 / W2 chunks: 1024 floats each = 256 float4, 1 per thread ----
    {
        int ql = t >> 3, g = t & 7;
        float4 vb = ((const float4*)(b1 + (long)qb * U))[t];
        *(float4*)&b1s[ql * BW_STRIDE + g * 4] = vb;
        float4 vw = ((const float4*)(W2 + (long)qb * U))[t];
        *(float4*)&w2s[ql * BW_STRIDE + g * 4] = vw;
    }
    if (t < QC) b2s[t] = b2[qb + t];
    __syncthreads();

    const int  ql  = t & 31;
    const int  grp = t >> 5;
    const long r0  = rbase + (long)grp * NR;
    const long rlast = (long)B - 1;

    // ---- load x: NR rows x 8 floats (2 float4 per row), coalesced ----
    float xr[NR][8];
    #pragma unroll
    for (int i = 0; i < NR; ++i) {
        long r = r0 + i; if (r > rlast) r = rlast;   // clamp (B%RPB==0 normally)
        const float4* xp = (const float4*)(x + r * (Q * S) + (long)(qb + ql) * S);
        float4 a = xp[0], bqv = xp[1];
        xr[i][0] = a.x;  xr[i][1] = a.y;  xr[i][2] = a.z;  xr[i][3] = a.w;
        xr[i][4] = bqv.x; xr[i][5] = bqv.y; xr[i][6] = bqv.z; xr[i][7] = bqv.w;
    }

    // ---- h init from b1 ----
    float h[NR][U];
    #pragma unroll
    for (int u4 = 0; u4 < 8; ++u4) {
        float4 bb = *(const float4*)&b1s[ql * BW_STRIDE + u4 * 4];
        #pragma unroll
        for (int i = 0; i < NR; ++i) {
            h[i][u4*4+0] = bb.x; h[i][u4*4+1] = bb.y;
            h[i][u4*4+2] = bb.z; h[i][u4*4+3] = bb.w;
        }
    }

    // ---- GEMM1: h[i][u] += x[i][s] * W1[q][s][u] ----
    #pragma unroll
    for (int s = 0; s < S; ++s) {
        #pragma unroll
        for (int u4 = 0; u4 < 8; ++u4) {
            float4 w = *(const float4*)&w1s[ql * W1_STRIDE + s * U + u4 * 4];
            #pragma unroll
            for (int i = 0; i < NR; ++i) {
                h[i][u4*4+0] = fmaf(xr[i][s], w.x, h[i][u4*4+0]);
                h[i][u4*4+1] = fmaf(xr[i][s], w.y, h[i][u4*4+1]);
                h[i][u4*4+2] = fmaf(xr[i][s], w.z, h[i][u4*4+2]);
                h[i][u4*4+3] = fmaf(xr[i][s], w.w, h[i][u4*4+3]);
            }
        }
    }

    // ---- ELU + GEMM2: out = b2 + sum_u elu(h) * W2[q][u] ----
    float acc[NR];
    #pragma unroll
    for (int i = 0; i < NR; ++i) acc[i] = b2s[ql];

    #pragma unroll
    for (int u4 = 0; u4 < 8; ++u4) {
        float4 w = *(const float4*)&w2s[ql * BW_STRIDE + u4 * 4];
        float wv[4] = {w.x, w.y, w.z, w.w};
        #pragma unroll
        for (int i = 0; i < NR; ++i) {
            #pragma unroll
            for (int j = 0; j < 4; ++j) {
                float v = h[i][u4*4+j];
                // elu(v) = max(v, exp(min(v,0)) - 1)  (branch-free, overflow-safe)
                float e = __expf(fminf(v, 0.f)) - 1.f;
                float r = fmaxf(v, e);
                acc[i]  = fmaf(r, wv[j], acc[i]);
            }
        }
    }

    #pragma unroll
    for (int i = 0; i < NR; ++i) {
        long r = r0 + i;
        if (r < B) out[r * Q + qb + ql] = acc[i];
    }
}

extern "C" void kernel_launch(void* const* d_in, const int* in_sizes, int n_in,
                              void* d_out, int out_size, void* d_ws, size_t ws_size,
                              hipStream_t stream) {
    const float* x  = (const float*)d_in[0];
    const float* W1 = (const float*)d_in[1];
    const float* b1 = (const float*)d_in[2];
    const float* W2 = (const float*)d_in[3];
    const float* b2 = (const float*)d_in[4];
    float* out = (float*)d_out;

    const int B = in_sizes[0] / (Q * S);
    const int nblocks = ((B + RPB - 1) / RPB) * (Q / QC);
    hipLaunchKernelGGL(divenc_kernel, dim3(nblocks), dim3(256), 0, stream,
                       x, W1, b1, W2, b2, out, B);
}

// Round 2
// 976.398 us; speedup vs baseline: 1.6817x; 1.6817x over previous
//
#include <hip/hip_runtime.h>

// B=65536, Q=128, S=8, U=32. out[b,q] = b2[q] + sum_u elu(b1[q,u] + sum_s x[b,q,s]*W1[q,s,u]) * W2[q,u]
#define Q    128
#define S    8
#define U    32
#define QC   32            // q per block (4 chunks cover Q)
#define NR   4             // rows per thread
#define GRPS 8             // row groups per block (256 threads / 32 q)
#define RPB  (NR * GRPS)   // 32 rows per block

__global__ __launch_bounds__(256)
__attribute__((amdgpu_waves_per_eu(2, 4)))
void divenc_kernel(const float* __restrict__ x, const float* __restrict__ W1,
                   const float* __restrict__ b1, const float* __restrict__ W2,
                   const float* __restrict__ b2, float* __restrict__ out, int B)
{
    // Chunk-major, XOR-swizzled LDS (T2-style): slot [c][q ^ (c&31)].
    // Both ds_write (staging) and ds_read (compute) are consecutive-float4
    // per lane after the bijective XOR -> conflict-free both sides.
    __shared__ float4 w1t[64 * 32];   // 32 KB: chunk c = s*8+u4
    __shared__ float4 b1t[8 * 32];    //  4 KB: chunk c = u4
    __shared__ float4 w2t[8 * 32];    //  4 KB: chunk c = u4
    // total 40 KB -> 4 blocks/CU LDS ceiling

    const int  t     = threadIdx.x;
    const int  bid   = blockIdx.x;
    const int  qb    = (bid & 3) * QC;
    const long rbase = (long)(bid >> 2) * RPB;

    // ---- stage W1 chunk: 2048 float4, coalesced global read ----
    {
        const float4* W1v = (const float4*)(W1 + (long)qb * (S * U));
        #pragma unroll
        for (int k = 0; k < 8; ++k) {
            int    i = t + k * 256;       // global float4 index within chunk
            float4 v = W1v[i];
            int qp = i >> 6;              // source q (0..31)
            int c  = i & 63;              // chunk = s*8 + u4
            w1t[c * 32 + (qp ^ (c & 31))] = v;
        }
    }
    // ---- stage b1 / W2 chunks: 256 float4 each ----
    {
        int qp = t >> 3, c = t & 7;
        b1t[c * 32 + (qp ^ c)] = ((const float4*)(b1 + (long)qb * U))[t];
        w2t[c * 32 + (qp ^ c)] = ((const float4*)(W2 + (long)qb * U))[t];
    }

    const int  ql  = t & 31;
    const int  grp = t >> 5;
    const long r0  = rbase + (long)grp * NR;
    const float b2v = b2[qb + ql];
    __syncthreads();

    // ---- load x: NR rows x 8 floats, half-wave reads 1KB contiguous ----
    float xr[NR][8];
    const long rlast = (long)B - 1;
    #pragma unroll
    for (int i = 0; i < NR; ++i) {
        long r = r0 + i; if (r > rlast) r = rlast;
        const float4* xp = (const float4*)(x + r * (long)(Q * S) + (long)(qb + ql) * S);
        float4 a = xp[0], bv = xp[1];
        xr[i][0] = a.x;  xr[i][1] = a.y;  xr[i][2] = a.z;  xr[i][3] = a.w;
        xr[i][4] = bv.x; xr[i][5] = bv.y; xr[i][6] = bv.z; xr[i][7] = bv.w;
    }

    float acc[NR];
    #pragma unroll
    for (int i = 0; i < NR; ++i) acc[i] = b2v;

    // ---- process U in quarters of 8 -> h liveness = NR*8 = 32 VGPRs ----
    #pragma unroll
    for (int up = 0; up < 4; ++up) {
        float h[NR][8];
        #pragma unroll
        for (int half = 0; half < 2; ++half) {
            int    c  = up * 2 + half;
            float4 bb = b1t[c * 32 + (ql ^ c)];
            #pragma unroll
            for (int i = 0; i < NR; ++i) {
                h[i][half*4+0] = bb.x; h[i][half*4+1] = bb.y;
                h[i][half*4+2] = bb.z; h[i][half*4+3] = bb.w;
            }
        }
        #pragma unroll
        for (int s = 0; s < S; ++s) {
            #pragma unroll
            for (int half = 0; half < 2; ++half) {
                int    c = s * 8 + up * 2 + half;
                float4 w = w1t[c * 32 + (ql ^ (c & 31))];
                #pragma unroll
                for (int i = 0; i < NR; ++i) {
                    h[i][half*4+0] = fmaf(xr[i][s], w.x, h[i][half*4+0]);
                    h[i][half*4+1] = fmaf(xr[i][s], w.y, h[i][half*4+1]);
                    h[i][half*4+2] = fmaf(xr[i][s], w.z, h[i][half*4+2]);
                    h[i][half*4+3] = fmaf(xr[i][s], w.w, h[i][half*4+3]);
                }
            }
        }
        #pragma unroll
        for (int half = 0; half < 2; ++half) {
            int    c = up * 2 + half;
            float4 w = w2t[c * 32 + (ql ^ c)];
            float  wv[4] = {w.x, w.y, w.z, w.w};
            #pragma unroll
            for (int i = 0; i < NR; ++i) {
                #pragma unroll
                for (int j = 0; j < 4; ++j) {
                    float v = h[i][half*4+j];
                    // elu(v) = max(v, exp(min(v,0)) - 1), branch-free
                    float e = __expf(fminf(v, 0.f)) - 1.f;
                    acc[i]  = fmaf(fmaxf(v, e), wv[j], acc[i]);
                }
            }
        }
    }

    #pragma unroll
    for (int i = 0; i < NR; ++i) {
        long r = r0 + i;
        if (r < B) out[r * Q + qb + ql] = acc[i];
    }
}

extern "C" void kernel_launch(void* const* d_in, const int* in_sizes, int n_in,
                              void* d_out, int out_size, void* d_ws, size_t ws_size,
                              hipStream_t stream) {
    const float* x  = (const float*)d_in[0];
    const float* W1 = (const float*)d_in[1];
    const float* b1 = (const float*)d_in[2];
    const float* W2 = (const float*)d_in[3];
    const float* b2 = (const float*)d_in[4];
    float* out = (float*)d_out;

    const int B = in_sizes[0] / (Q * S);
    const int nblocks = ((B + RPB - 1) / RPB) * (Q / QC);
    hipLaunchKernelGGL(divenc_kernel, dim3(nblocks), dim3(256), 0, stream,
                       x, W1, b1, W2, b2, out, B);
}

// Round 3
// 113.380 us; speedup vs baseline: 14.4819x; 8.6117x over previous
//
#include <hip/hip_runtime.h>

// B=65536, Q=128, S=8, U=32
// out[b,q] = b2[q] + sum_u elu(b1[q,u] + sum_s x[b,q,s]*W1[q,s,u]) * W2[q,u]
#define Q    128
#define S    8
#define U    32
#define QC   32            // q per block (4 chunks cover Q)
#define NR   4             // rows per thread
#define GRPS 8             // row groups per block
#define RPB  (NR * GRPS)   // 32 rows per block

__global__ __launch_bounds__(256)
__attribute__((amdgpu_waves_per_eu(4, 4)))   // budget=128 VGPR; LDS caps at 4 waves/EU anyway
void divenc_kernel(const float* __restrict__ x, const float* __restrict__ W1,
                   const float* __restrict__ b1, const float* __restrict__ W2,
                   const float* __restrict__ b2, float* __restrict__ out, int B)
{
    // Chunk-major, XOR-swizzled LDS (R2-verified: 0 bank conflicts both sides).
    __shared__ float4 w1t[64 * 32];   // 32 KB: chunk c = s*8 + u4
    __shared__ float4 b1t[8 * 32];    //  4 KB
    __shared__ float4 w2t[8 * 32];    //  4 KB

    const int t     = threadIdx.x;
    const int bid   = blockIdx.x;
    const int qb    = (bid & 3) * QC;
    const int rbase = (bid >> 2) * RPB;

    // ---- stage W1 chunk: 2048 float4, coalesced ----
    {
        const float4* W1v = (const float4*)(W1 + (size_t)qb * (S * U));
        #pragma unroll
        for (int k = 0; k < 8; ++k) {
            int    i = t + k * 256;
            float4 v = W1v[i];
            int qp = i >> 6;
            int c  = i & 63;
            w1t[c * 32 + (qp ^ (c & 31))] = v;
        }
    }
    // ---- stage b1 / W2: 256 float4 each ----
    {
        int qp = t >> 3, c = t & 7;
        b1t[c * 32 + (qp ^ c)] = ((const float4*)(b1 + (size_t)qb * U))[t];
        w2t[c * 32 + (qp ^ c)] = ((const float4*)(W2 + (size_t)qb * U))[t];
    }

    const int   ql   = t & 31;
    const int   grp  = t >> 5;
    const int   r0   = rbase + grp * NR;
    const int   rmax = B - 1;
    const float b2v  = b2[qb + ql];
    __syncthreads();

    // ---- x rows in NAMED float4 registers (no arrays -> no scratch) ----
    float4 xa0, xa1, xa2, xa3;   // s = 0..3
    float4 xb0, xb1, xb2, xb3;   // s = 4..7
#define LOADX(I) { int r_ = r0 + I; if (r_ > rmax) r_ = rmax;                        \
        const float4* xp_ = (const float4*)x + (size_t)r_ * (Q * S / 4)              \
                            + (qb + ql) * (S / 4);                                   \
        xa##I = xp_[0]; xb##I = xp_[1]; }
    LOADX(0) LOADX(1) LOADX(2) LOADX(3)
#undef LOADX

    float acc0 = b2v, acc1 = b2v, acc2 = b2v, acc3 = b2v;

#define FMA4(H, XS) { H.x = fmaf(XS, w_.x, H.x); H.y = fmaf(XS, w_.y, H.y);          \
                      H.z = fmaf(XS, w_.z, H.z); H.w = fmaf(XS, w_.w, H.w); }
#define STEPA(SI, C) { const int c_ = SI * 8 + c8;                                   \
        const float4 w_ = w1t[c_ * 32 + (ql ^ (c_ & 31))];                           \
        FMA4(h0, xa0.C) FMA4(h1, xa1.C) FMA4(h2, xa2.C) FMA4(h3, xa3.C) }
#define STEPB(SI, C) { const int c_ = SI * 8 + c8;                                   \
        const float4 w_ = w1t[c_ * 32 + (ql ^ (c_ & 31))];                           \
        FMA4(h0, xb0.C) FMA4(h1, xb1.C) FMA4(h2, xb2.C) FMA4(h3, xb3.C) }
// elu(v) = max(v, exp(min(v,0)) - 1), branch-free, overflow-safe
#define EL(ACC, HV, WC) { float v_ = HV; float e_ = __expf(fminf(v_, 0.f)) - 1.f;    \
                          ACC = fmaf(fmaxf(v_, e_), WC, ACC); }

    // ---- U in 8 chunks of 4; rolled loop bounds register liveness ----
    #pragma unroll 1
    for (int c8 = 0; c8 < 8; ++c8) {
        const float4 bb = b1t[c8 * 32 + (ql ^ c8)];
        float4 h0 = bb, h1 = bb, h2 = bb, h3 = bb;

        STEPA(0, x) STEPA(1, y) STEPA(2, z) STEPA(3, w)
        STEPB(4, x) STEPB(5, y) STEPB(6, z) STEPB(7, w)

        const float4 w2v = w2t[c8 * 32 + (ql ^ c8)];
        EL(acc0, h0.x, w2v.x) EL(acc0, h0.y, w2v.y) EL(acc0, h0.z, w2v.z) EL(acc0, h0.w, w2v.w)
        EL(acc1, h1.x, w2v.x) EL(acc1, h1.y, w2v.y) EL(acc1, h1.z, w2v.z) EL(acc1, h1.w, w2v.w)
        EL(acc2, h2.x, w2v.x) EL(acc2, h2.y, w2v.y) EL(acc2, h2.z, w2v.z) EL(acc2, h2.w, w2v.w)
        EL(acc3, h3.x, w2v.x) EL(acc3, h3.y, w2v.y) EL(acc3, h3.z, w2v.z) EL(acc3, h3.w, w2v.w)
    }
#undef FMA4
#undef STEPA
#undef STEPB
#undef EL

#define STORE(I, ACC) { int r_ = r0 + I;                                             \
        if (r_ < B) out[(size_t)r_ * Q + qb + ql] = ACC; }
    STORE(0, acc0) STORE(1, acc1) STORE(2, acc2) STORE(3, acc3)
#undef STORE
}

extern "C" void kernel_launch(void* const* d_in, const int* in_sizes, int n_in,
                              void* d_out, int out_size, void* d_ws, size_t ws_size,
                              hipStream_t stream) {
    const float* x  = (const float*)d_in[0];
    const float* W1 = (const float*)d_in[1];
    const float* b1 = (const float*)d_in[2];
    const float* W2 = (const float*)d_in[3];
    const float* b2 = (const float*)d_in[4];
    float* out = (float*)d_out;

    const int B = in_sizes[0] / (Q * S);
    const int nblocks = ((B + RPB - 1) / RPB) * (Q / QC);
    hipLaunchKernelGGL(divenc_kernel, dim3(nblocks), dim3(256), 0, stream,
                       x, W1, b1, W2, b2, out, B);
}

// Round 4
// 112.058 us; speedup vs baseline: 14.6528x; 1.0118x over previous
//
#include <hip/hip_runtime.h>

// B=65536, Q=128, S=8, U=32
// out[b,q] = b2[q] + sum_u elu(b1[q,u] + sum_s x[b,q,s]*W1[q,s,u]) * W2[q,u]
#define Q    128
#define S    8
#define U    32
#define QC   32            // q per block (4 chunks cover Q)
#define NR   4             // rows per thread
#define GRPS 8             // row groups per block
#define RPB  (NR * GRPS)   // 32 rows per block

__global__ __launch_bounds__(256)
__attribute__((amdgpu_waves_per_eu(4, 4)))   // pin budget=128 VGPR (16 waves/CU; LDS allows 4 blocks/CU)
void divenc_kernel(const float* __restrict__ x, const float* __restrict__ W1,
                   const float* __restrict__ b1, const float* __restrict__ W2,
                   const float* __restrict__ b2, float* __restrict__ out, int B)
{
    // Chunk-major, XOR-swizzled LDS (verified: 0 bank conflicts both sides).
    __shared__ float4 w1t[64 * 32];   // 32 KB: chunk c = s*8 + u4
    __shared__ float4 b1t[8 * 32];    //  4 KB
    __shared__ float4 w2t[8 * 32];    //  4 KB

    const int t     = threadIdx.x;
    const int bid   = blockIdx.x;
    const int qb    = (bid & 3) * QC;
    const int rbase = (bid >> 2) * RPB;

    // ---- stage W1 chunk: 2048 float4, coalesced ----
    {
        const float4* W1v = (const float4*)(W1 + (size_t)qb * (S * U));
        #pragma unroll
        for (int k = 0; k < 8; ++k) {
            int    i = t + k * 256;
            float4 v = W1v[i];
            int qp = i >> 6;
            int c  = i & 63;
            w1t[c * 32 + (qp ^ (c & 31))] = v;
        }
    }
    // ---- stage b1 / W2: 256 float4 each ----
    {
        int qp = t >> 3, c = t & 7;
        b1t[c * 32 + (qp ^ c)] = ((const float4*)(b1 + (size_t)qb * U))[t];
        w2t[c * 32 + (qp ^ c)] = ((const float4*)(W2 + (size_t)qb * U))[t];
    }

    const int   ql   = t & 31;
    const int   grp  = t >> 5;
    const int   r0   = rbase + grp * NR;
    const int   rmax = B - 1;
    const float b2v  = b2[qb + ql];
    __syncthreads();

    // ---- x rows in NAMED float4 registers (no arrays -> no scratch) ----
    float4 xa0, xa1, xa2, xa3;   // s = 0..3
    float4 xb0, xb1, xb2, xb3;   // s = 4..7
#define LOADX(I) { int r_ = r0 + I; if (r_ > rmax) r_ = rmax;                        \
        const float4* xp_ = (const float4*)x + (size_t)r_ * (Q * S / 4)              \
                            + (qb + ql) * (S / 4);                                   \
        xa##I = xp_[0]; xb##I = xp_[1]; }
    LOADX(0) LOADX(1) LOADX(2) LOADX(3)
#undef LOADX

    float acc0 = b2v, acc1 = b2v, acc2 = b2v, acc3 = b2v;

#define FMA4(H, XS) { H.x = fmaf(XS, w_.x, H.x); H.y = fmaf(XS, w_.y, H.y);          \
                      H.z = fmaf(XS, w_.z, H.z); H.w = fmaf(XS, w_.w, H.w); }
#define STEPA(SI, C) { const int c_ = SI * 8 + c8;                                   \
        const float4 w_ = w1t[c_ * 32 + (ql ^ (c_ & 31))];                           \
        FMA4(h0, xa0.C) FMA4(h1, xa1.C) FMA4(h2, xa2.C) FMA4(h3, xa3.C) }
#define STEPB(SI, C) { const int c_ = SI * 8 + c8;                                   \
        const float4 w_ = w1t[c_ * 32 + (ql ^ (c_ & 31))];                           \
        FMA4(h0, xb0.C) FMA4(h1, xb1.C) FMA4(h2, xb2.C) FMA4(h3, xb3.C) }
// elu(v) = max(v, exp(min(v,0)) - 1), branch-free, overflow-safe
#define EL(ACC, HV, WC) { float v_ = HV; float e_ = __expf(fminf(v_, 0.f)) - 1.f;    \
                          ACC = fmaf(fmaxf(v_, e_), WC, ACC); }

    // ---- U in 8 chunks of 4; unroll 2: overlap chunk c+1 LDS reads under
    // chunk c FMA/ELU tail (ILP for latency hiding at 4 waves/SIMD), while
    // keeping liveness ~2 iterations (named scalars only -> no scratch) ----
    #pragma unroll 2
    for (int c8 = 0; c8 < 8; ++c8) {
        const float4 bb = b1t[c8 * 32 + (ql ^ c8)];
        float4 h0 = bb, h1 = bb, h2 = bb, h3 = bb;

        STEPA(0, x) STEPA(1, y) STEPA(2, z) STEPA(3, w)
        STEPB(4, x) STEPB(5, y) STEPB(6, z) STEPB(7, w)

        const float4 w2v = w2t[c8 * 32 + (ql ^ c8)];
        EL(acc0, h0.x, w2v.x) EL(acc0, h0.y, w2v.y) EL(acc0, h0.z, w2v.z) EL(acc0, h0.w, w2v.w)
        EL(acc1, h1.x, w2v.x) EL(acc1, h1.y, w2v.y) EL(acc1, h1.z, w2v.z) EL(acc1, h1.w, w2v.w)
        EL(acc2, h2.x, w2v.x) EL(acc2, h2.y, w2v.y) EL(acc2, h2.z, w2v.z) EL(acc2, h2.w, w2v.w)
        EL(acc3, h3.x, w2v.x) EL(acc3, h3.y, w2v.y) EL(acc3, h3.z, w2v.z) EL(acc3, h3.w, w2v.w)
    }
#undef FMA4
#undef STEPA
#undef STEPB
#undef EL

#define STORE(I, ACC) { int r_ = r0 + I;                                             \
        if (r_ < B) out[(size_t)r_ * Q + qb + ql] = ACC; }
    STORE(0, acc0) STORE(1, acc1) STORE(2, acc2) STORE(3, acc3)
#undef STORE
}

extern "C" void kernel_launch(void* const* d_in, const int* in_sizes, int n_in,
                              void* d_out, int out_size, void* d_ws, size_t ws_size,
                              hipStream_t stream) {
    const float* x  = (const float*)d_in[0];
    const float* W1 = (const float*)d_in[1];
    const float* b1 = (const float*)d_in[2];
    const float* W2 = (const float*)d_in[3];
    const float* b2 = (const float*)d_in[4];
    float* out = (float*)d_out;

    const int B = in_sizes[0] / (Q * S);
    const int nblocks = ((B + RPB - 1) / RPB) * (Q / QC);
    hipLaunchKernelGGL(divenc_kernel, dim3(nblocks), dim3(256), 0, stream,
                       x, W1, b1, W2, b2, out, B);
}